// Round 18
// baseline (36.513 us; speedup 1.0000x reference)
//
#include <hip/hip_runtime.h>
#include <hip/hip_bf16.h>

// out[i][j] = (x@beta)[i][j] - 0.1*y[i][j]*||beta[:,j]||_1
//             + (4096*rowsum(W2)[j] + bias2[j] + bias_lin[j])
// M=4096, K=2048, N=1024. adv==1 always.
//
// Round 18: r17 + y prefetched into registers at kernel ENTRY (independent of
// the K-loop; oldest VMEM ops so counted-vmcnt discipline unchanged). Removes
// the serialized 16MB y-read tail from the epilogue.

typedef float    f32x4  __attribute__((ext_vector_type(4)));
typedef unsigned u32x4  __attribute__((ext_vector_type(4)));
typedef long     lx2    __attribute__((ext_vector_type(2)));

constexpr int M = 4096;
constexpr int N = 1024;
constexpr int K = 2048;
constexpr int NHID = 4096;

__device__ __forceinline__ unsigned pk4f8(float a, float b, float c, float d) {
    unsigned v = __builtin_amdgcn_cvt_pk_fp8_f32(a, b, 0, false);
    v = __builtin_amdgcn_cvt_pk_fp8_f32(c, d, v, true);
    return v;
}

__device__ __forceinline__ void gll16(const void* g, void* l) {
    __builtin_amdgcn_global_load_lds(
        (const __attribute__((address_space(1))) void*)g,
        (__attribute__((address_space(3))) void*)l, 16, 0, 0);
}

// =================== pre (identical to round 12) ============================
__global__ void __launch_bounds__(256) pre_kernel(
    const float* __restrict__ x, const float* __restrict__ beta,
    const float* __restrict__ W2,
    char* __restrict__ xb, char* __restrict__ bt,
    float* __restrict__ partials,   // [32][1024]
    float* __restrict__ wsum) {     // [1024]
    __shared__ float tls[64 * 132];
    const int bx = blockIdx.x, tid = threadIdx.x;
    if (bx < 1024) {
        const int rt = bx >> 4, kt = bx & 15;
        {
            const int r = tid >> 2, c0 = (tid & 3) * 32;
            const float* src = x + (size_t)(rt * 64 + r) * K + kt * 128 + c0;
            #pragma unroll
            for (int i = 0; i < 8; ++i)
                *(f32x4*)&tls[r * 132 + c0 + i * 4] = *(const f32x4*)(src + i * 4);
        }
        __syncthreads();
        {
            const int r = tid >> 2;
            const float* row = &tls[r * 132];
            char* orow = xb + (size_t)(rt * 64 + r) * K + kt * 128;
            #pragma unroll
            for (int uu = 0; uu < 2; ++uu) {
                const int u = (tid & 3) + uu * 4;
                const int p = u >> 2, q = u & 3;
                const float* h0 = row + p * 64 + q * 8;
                const float* h1 = h0 + 32;
                u32x4 o = { pk4f8(h0[0], h0[1], h0[2], h0[3]),
                            pk4f8(h0[4], h0[5], h0[6], h0[7]),
                            pk4f8(h1[0], h1[1], h1[2], h1[3]),
                            pk4f8(h1[4], h1[5], h1[6], h1[7]) };
                *(u32x4*)(orow + u * 16) = o;
            }
        }
    } else if (bx < 1536) {
        const int tile = bx - 1024, tk = tile & 31, tn = tile >> 5;
        {
            const int r = tid >> 2, c0 = (tid & 3) * 16;
            const float* src = beta + (size_t)(tk * 64 + r) * N + tn * 64 + c0;
            #pragma unroll
            for (int j = 0; j < 4; ++j)
                *(f32x4*)&tls[r * 68 + c0 + j * 4] = *(const f32x4*)(src + j * 4);
        }
        __syncthreads();
        {
            const int n = tid >> 2, q = tid & 3;
            float s = 0.f;
            float v0[8], v1[8];
            #pragma unroll
            for (int j = 0; j < 8; ++j) {
                v0[j] = tls[(q * 8 + j) * 68 + n];
                v1[j] = tls[(32 + q * 8 + j) * 68 + n];
                s += fabsf(v0[j]) + fabsf(v1[j]);
            }
            s += __shfl_xor(s, 1);
            s += __shfl_xor(s, 2);
            if (q == 0) partials[tk * 1024 + tn * 64 + n] = s;
            u32x4 o = { pk4f8(v0[0], v0[1], v0[2], v0[3]),
                        pk4f8(v0[4], v0[5], v0[6], v0[7]),
                        pk4f8(v1[0], v1[1], v1[2], v1[3]),
                        pk4f8(v1[4], v1[5], v1[6], v1[7]) };
            *(u32x4*)(bt + (size_t)(tn * 64 + n) * K + tk * 64 + q * 16) = o;
        }
    } else {
        const int b = bx - 1536;
        const int wv = tid >> 6, lane = tid & 63;
        const int row = b * 4 + wv;
        const f32x4* w4 = (const f32x4*)(W2 + (size_t)row * NHID);
        float acc = 0.f;
        #pragma unroll
        for (int i = 0; i < 16; ++i) {
            f32x4 v = w4[i * 64 + lane];
            acc += v[0] + v[1] + v[2] + v[3];
        }
        #pragma unroll
        for (int off = 32; off; off >>= 1) acc += __shfl_down(acc, off);
        if (lane == 0) wsum[row] = acc;
    }
}

// =================== main GEMM (r17 + y-prefetch at entry) ==================
constexpr int BKu = 128;
constexpr int NT  = K / BKu;         // 16
constexpr int ASZ = 128 * BKu;       // 16384 B
constexpr int BSZ = 64 * BKu;        // 8192 B

__global__ void __launch_bounds__(512, 4) gemm_kernel(
    const char* __restrict__ xb, const char* __restrict__ bt,
    const float* __restrict__ y,
    const float* __restrict__ partials, const float* __restrict__ wsum,
    const float* __restrict__ bias_lin, const float* __restrict__ bias2,
    float* __restrict__ out) {
    __shared__ __align__(16) char Al[3 * ASZ];   // 48KB (epilogue scratch T)
    __shared__ __align__(16) char Bl[3 * BSZ];   // 24KB (epilogue bev/ctv)

    const int tid = threadIdx.x, lane = tid & 63, w = tid >> 6;   // w: 0..7
    const int wm = w >> 1, wn = w & 1;                            // 4m x 2n
    const int c = blockIdx.x & 7, local = blockIdx.x >> 3;
    const int mb = ((c & 1) << 4) + (local >> 2);
    const int nb = ((c >> 1) << 2) + (local & 3);
    const int brow = mb * 128, bcol = nb * 64;

    // ---- y prefetch (independent of K-loop; oldest VMEM ops) ----
    const int c4 = tid & 15, r0 = tid >> 4;      // rows r0+32i, col c4*4
    f32x4 yv[4];
    #pragma unroll
    for (int i = 0; i < 4; ++i) {
        const size_t idx = (size_t)(brow + r0 + i * 32) * N + bcol + c4 * 4;
        yv[i] = *(const f32x4*)&y[idx];
    }

    // ---- staging (per-lane source swizzle, linear LDS dest) ----
    const int srow = lane >> 3;
    const int sulog = (lane & 7) ^ srow;
    const char* asrc0 = xb + (size_t)(brow + w * 16 + srow) * K + sulog * 16;
    const char* asrc1 = asrc0 + (size_t)8 * K;
    const char* bsrc  = bt + (size_t)(bcol + w * 8 + srow) * K + sulog * 16;

    auto STAGE = [&](int buf, int t) {
        gll16(asrc0 + t * BKu, &Al[buf * ASZ + w * 2048]);
        gll16(asrc1 + t * BKu, &Al[buf * ASZ + w * 2048 + 1024]);
        gll16(bsrc  + t * BKu, &Bl[buf * BSZ + w * 1024]);
    };

    // ---- fragment read offsets ----
    const int r = lane & 15, q = lane >> 4;
    int aoff[2][2], boff[2][2];
    #pragma unroll
    for (int m = 0; m < 2; ++m)
        #pragma unroll
        for (int p = 0; p < 2; ++p) {
            const int row = wm * 32 + m * 16 + r;
            aoff[m][p] = row * 128 + (((p * 4 + q) ^ (r & 7)) * 16);
        }
    #pragma unroll
    for (int n = 0; n < 2; ++n)
        #pragma unroll
        for (int p = 0; p < 2; ++p) {
            const int row = wn * 32 + n * 16 + r;
            boff[n][p] = row * 128 + (((p * 4 + q) ^ (r & 7)) * 16);
        }

    f32x4 acc[2][2];
    #pragma unroll
    for (int m = 0; m < 2; ++m)
        #pragma unroll
        for (int n = 0; n < 2; ++n) acc[m][n] = (f32x4)0.f;

    auto COMPUTE = [&](int buf) {
        const char* A = &Al[buf * ASZ];
        const char* B = &Bl[buf * BSZ];
        #pragma unroll
        for (int p = 0; p < 2; ++p) {
            lx2 a0 = *(const lx2*)&A[aoff[0][p]];
            lx2 a1 = *(const lx2*)&A[aoff[1][p]];
            lx2 b0 = *(const lx2*)&B[boff[0][p]];
            lx2 b1 = *(const lx2*)&B[boff[1][p]];
            acc[0][0] = __builtin_amdgcn_mfma_f32_16x16x32_fp8_fp8(a0.x, b0.x, acc[0][0], 0, 0, 0);
            acc[0][1] = __builtin_amdgcn_mfma_f32_16x16x32_fp8_fp8(a0.x, b1.x, acc[0][1], 0, 0, 0);
            acc[1][0] = __builtin_amdgcn_mfma_f32_16x16x32_fp8_fp8(a1.x, b0.x, acc[1][0], 0, 0, 0);
            acc[1][1] = __builtin_amdgcn_mfma_f32_16x16x32_fp8_fp8(a1.x, b1.x, acc[1][1], 0, 0, 0);
            acc[0][0] = __builtin_amdgcn_mfma_f32_16x16x32_fp8_fp8(a0.y, b0.y, acc[0][0], 0, 0, 0);
            acc[0][1] = __builtin_amdgcn_mfma_f32_16x16x32_fp8_fp8(a0.y, b1.y, acc[0][1], 0, 0, 0);
            acc[1][0] = __builtin_amdgcn_mfma_f32_16x16x32_fp8_fp8(a1.y, b0.y, acc[1][0], 0, 0, 0);
            acc[1][1] = __builtin_amdgcn_mfma_f32_16x16x32_fp8_fp8(a1.y, b1.y, acc[1][1], 0, 0, 0);
        }
    };

    STAGE(0, 0);
    STAGE(1, 1);
    for (int t = 0; t < NT; ++t) {
        if (t < NT - 1) { asm volatile("s_waitcnt vmcnt(3)" ::: "memory"); }
        else            { asm volatile("s_waitcnt vmcnt(0)" ::: "memory"); }
        __builtin_amdgcn_s_barrier();
        __builtin_amdgcn_sched_barrier(0);
        if (t + 2 < NT) STAGE((t + 2) % 3, t + 2);
        COMPUTE(t % 3);
    }

    // ---- vectorized epilogue (y already in registers) ----
    __syncthreads();                       // staging LDS now free
    float* T   = (float*)Al;               // [128][66] floats = 33792B < 48KB
    float* bev = (float*)Bl;               // [64]
    float* ctv = bev + 64;                 // [64]

    #pragma unroll
    for (int m = 0; m < 2; ++m)
        #pragma unroll
        for (int n = 0; n < 2; ++n) {
            const int lr = wm * 32 + m * 16 + q * 4;
            const int lc = wn * 32 + n * 16 + r;
            #pragma unroll
            for (int rr = 0; rr < 4; ++rr)
                T[(lr + rr) * 66 + lc] = acc[m][n][rr];
        }
    if (tid < 64) {
        const int gc = bcol + tid;
        float bsum = 0.f;
        #pragma unroll 8
        for (int tk = 0; tk < 32; ++tk) bsum += partials[tk * 1024 + gc];
        bev[tid] = 0.1f * bsum;
        ctv[tid] = bias_lin[gc] + bias2[gc] + (float)NHID * wsum[gc];
    }
    __syncthreads();

    const f32x4 ct4 = *(const f32x4*)&ctv[c4 * 4];
    const f32x4 be4 = *(const f32x4*)&bev[c4 * 4];
    #pragma unroll
    for (int i = 0; i < 4; ++i) {
        const int row = r0 + i * 32;
        f32x4 v = *(const f32x4*)&T[row * 66 + c4 * 4];
        const size_t idx = (size_t)(brow + row) * N + bcol + c4 * 4;
        f32x4 o;
        #pragma unroll
        for (int e = 0; e < 4; ++e) o[e] = v[e] + ct4[e] - be4[e] * yv[i][e];
        *(f32x4*)&out[idx] = o;
    }
}

extern "C" void kernel_launch(void* const* d_in, const int* in_sizes, int n_in,
                              void* d_out, int out_size, void* d_ws, size_t ws_size,
                              hipStream_t stream) {
    const float* x        = (const float*)d_in[0];
    const float* y        = (const float*)d_in[1];
    const float* beta     = (const float*)d_in[2];
    const float* bias_lin = (const float*)d_in[3];
    const float* W2       = (const float*)d_in[5];
    const float* bias2    = (const float*)d_in[7];
    float* out = (float*)d_out;

    float* partials = (float*)d_ws;                        // [32][1024]
    float* wsum     = partials + 32 * 1024;                // [1024]
    char*  xb       = (char*)(wsum + 1024);                // [M][K] fp8 permuted
    char*  bts      = xb + (size_t)M * K;                  // [N][K] fp8 permuted

    pre_kernel<<<1792, 256, 0, stream>>>(x, beta, W2, xb, bts, partials, wsum);
    gemm_kernel<<<512, 512, 0, stream>>>(xb, bts, y, partials, wsum,
                                         bias_lin, bias2, out);
}

// Round 19
// 34.682 us; speedup vs baseline: 1.0528x; 1.0528x over previous
//
#include <hip/hip_runtime.h>
#include <hip/hip_bf16.h>

// out[i][j] = (x@beta)[i][j] - 0.1*y[i][j]*||beta[:,j]||_1
//             + (4096*rowsum(W2)[j] + bias2[j] + bias_lin[j])
// M=4096, K=2048, N=1024. adv==1 always.
//
// Round 19 = Round 17 (best: 34.8us), reverting r18's y-prefetch regression.
// pre: x->fp8 k-permuted; beta->fp8 beta^T k-permuted + L1 partials (shfl,
//      atomic-free); W2 rowsums. ~15% above its 62MB HBM floor.
// gemm: fp8 16x16x32 MFMA, BM=128 BN=64 BKu=128 (NT=16), 8 waves, 3 LDS bufs,
//      lookahead-2 global_load_lds, counted vmcnt(3) (never drained in-loop),
//      zero-conflict ^(row&7) swizzle, vectorized LDS-bounce epilogue.

typedef float    f32x4  __attribute__((ext_vector_type(4)));
typedef unsigned u32x4  __attribute__((ext_vector_type(4)));
typedef long     lx2    __attribute__((ext_vector_type(2)));

constexpr int M = 4096;
constexpr int N = 1024;
constexpr int K = 2048;
constexpr int NHID = 4096;

__device__ __forceinline__ unsigned pk4f8(float a, float b, float c, float d) {
    unsigned v = __builtin_amdgcn_cvt_pk_fp8_f32(a, b, 0, false);
    v = __builtin_amdgcn_cvt_pk_fp8_f32(c, d, v, true);
    return v;
}

__device__ __forceinline__ void gll16(const void* g, void* l) {
    __builtin_amdgcn_global_load_lds(
        (const __attribute__((address_space(1))) void*)g,
        (__attribute__((address_space(3))) void*)l, 16, 0, 0);
}

// =================== pre (identical to round 12) ============================
__global__ void __launch_bounds__(256) pre_kernel(
    const float* __restrict__ x, const float* __restrict__ beta,
    const float* __restrict__ W2,
    char* __restrict__ xb, char* __restrict__ bt,
    float* __restrict__ partials,   // [32][1024]
    float* __restrict__ wsum) {     // [1024]
    __shared__ float tls[64 * 132];
    const int bx = blockIdx.x, tid = threadIdx.x;
    if (bx < 1024) {
        const int rt = bx >> 4, kt = bx & 15;
        {
            const int r = tid >> 2, c0 = (tid & 3) * 32;
            const float* src = x + (size_t)(rt * 64 + r) * K + kt * 128 + c0;
            #pragma unroll
            for (int i = 0; i < 8; ++i)
                *(f32x4*)&tls[r * 132 + c0 + i * 4] = *(const f32x4*)(src + i * 4);
        }
        __syncthreads();
        {
            const int r = tid >> 2;
            const float* row = &tls[r * 132];
            char* orow = xb + (size_t)(rt * 64 + r) * K + kt * 128;
            #pragma unroll
            for (int uu = 0; uu < 2; ++uu) {
                const int u = (tid & 3) + uu * 4;
                const int p = u >> 2, q = u & 3;
                const float* h0 = row + p * 64 + q * 8;
                const float* h1 = h0 + 32;
                u32x4 o = { pk4f8(h0[0], h0[1], h0[2], h0[3]),
                            pk4f8(h0[4], h0[5], h0[6], h0[7]),
                            pk4f8(h1[0], h1[1], h1[2], h1[3]),
                            pk4f8(h1[4], h1[5], h1[6], h1[7]) };
                *(u32x4*)(orow + u * 16) = o;
            }
        }
    } else if (bx < 1536) {
        const int tile = bx - 1024, tk = tile & 31, tn = tile >> 5;
        {
            const int r = tid >> 2, c0 = (tid & 3) * 16;
            const float* src = beta + (size_t)(tk * 64 + r) * N + tn * 64 + c0;
            #pragma unroll
            for (int j = 0; j < 4; ++j)
                *(f32x4*)&tls[r * 68 + c0 + j * 4] = *(const f32x4*)(src + j * 4);
        }
        __syncthreads();
        {
            const int n = tid >> 2, q = tid & 3;
            float s = 0.f;
            float v0[8], v1[8];
            #pragma unroll
            for (int j = 0; j < 8; ++j) {
                v0[j] = tls[(q * 8 + j) * 68 + n];
                v1[j] = tls[(32 + q * 8 + j) * 68 + n];
                s += fabsf(v0[j]) + fabsf(v1[j]);
            }
            s += __shfl_xor(s, 1);
            s += __shfl_xor(s, 2);
            if (q == 0) partials[tk * 1024 + tn * 64 + n] = s;
            u32x4 o = { pk4f8(v0[0], v0[1], v0[2], v0[3]),
                        pk4f8(v0[4], v0[5], v0[6], v0[7]),
                        pk4f8(v1[0], v1[1], v1[2], v1[3]),
                        pk4f8(v1[4], v1[5], v1[6], v1[7]) };
            *(u32x4*)(bt + (size_t)(tn * 64 + n) * K + tk * 64 + q * 16) = o;
        }
    } else {
        const int b = bx - 1536;
        const int wv = tid >> 6, lane = tid & 63;
        const int row = b * 4 + wv;
        const f32x4* w4 = (const f32x4*)(W2 + (size_t)row * NHID);
        float acc = 0.f;
        #pragma unroll
        for (int i = 0; i < 16; ++i) {
            f32x4 v = w4[i * 64 + lane];
            acc += v[0] + v[1] + v[2] + v[3];
        }
        #pragma unroll
        for (int off = 32; off; off >>= 1) acc += __shfl_down(acc, off);
        if (lane == 0) wsum[row] = acc;
    }
}

// =================== main GEMM (r12 K-loop + vectorized epilogue) ===========
constexpr int BKu = 128;
constexpr int NT  = K / BKu;         // 16
constexpr int ASZ = 128 * BKu;       // 16384 B
constexpr int BSZ = 64 * BKu;        // 8192 B

__global__ void __launch_bounds__(512, 4) gemm_kernel(
    const char* __restrict__ xb, const char* __restrict__ bt,
    const float* __restrict__ y,
    const float* __restrict__ partials, const float* __restrict__ wsum,
    const float* __restrict__ bias_lin, const float* __restrict__ bias2,
    float* __restrict__ out) {
    __shared__ __align__(16) char Al[3 * ASZ];   // 48KB (epilogue scratch T)
    __shared__ __align__(16) char Bl[3 * BSZ];   // 24KB (epilogue bev/ctv)

    const int tid = threadIdx.x, lane = tid & 63, w = tid >> 6;   // w: 0..7
    const int wm = w >> 1, wn = w & 1;                            // 4m x 2n
    const int c = blockIdx.x & 7, local = blockIdx.x >> 3;
    const int mb = ((c & 1) << 4) + (local >> 2);
    const int nb = ((c >> 1) << 2) + (local & 3);
    const int brow = mb * 128, bcol = nb * 64;

    // ---- staging (per-lane source swizzle, linear LDS dest) ----
    const int srow = lane >> 3;
    const int sulog = (lane & 7) ^ srow;
    const char* asrc0 = xb + (size_t)(brow + w * 16 + srow) * K + sulog * 16;
    const char* asrc1 = asrc0 + (size_t)8 * K;
    const char* bsrc  = bt + (size_t)(bcol + w * 8 + srow) * K + sulog * 16;

    auto STAGE = [&](int buf, int t) {
        gll16(asrc0 + t * BKu, &Al[buf * ASZ + w * 2048]);
        gll16(asrc1 + t * BKu, &Al[buf * ASZ + w * 2048 + 1024]);
        gll16(bsrc  + t * BKu, &Bl[buf * BSZ + w * 1024]);
    };

    // ---- fragment read offsets ----
    const int r = lane & 15, q = lane >> 4;
    int aoff[2][2], boff[2][2];
    #pragma unroll
    for (int m = 0; m < 2; ++m)
        #pragma unroll
        for (int p = 0; p < 2; ++p) {
            const int row = wm * 32 + m * 16 + r;
            aoff[m][p] = row * 128 + (((p * 4 + q) ^ (r & 7)) * 16);
        }
    #pragma unroll
    for (int n = 0; n < 2; ++n)
        #pragma unroll
        for (int p = 0; p < 2; ++p) {
            const int row = wn * 32 + n * 16 + r;
            boff[n][p] = row * 128 + (((p * 4 + q) ^ (r & 7)) * 16);
        }

    f32x4 acc[2][2];
    #pragma unroll
    for (int m = 0; m < 2; ++m)
        #pragma unroll
        for (int n = 0; n < 2; ++n) acc[m][n] = (f32x4)0.f;

    auto COMPUTE = [&](int buf) {
        const char* A = &Al[buf * ASZ];
        const char* B = &Bl[buf * BSZ];
        #pragma unroll
        for (int p = 0; p < 2; ++p) {
            lx2 a0 = *(const lx2*)&A[aoff[0][p]];
            lx2 a1 = *(const lx2*)&A[aoff[1][p]];
            lx2 b0 = *(const lx2*)&B[boff[0][p]];
            lx2 b1 = *(const lx2*)&B[boff[1][p]];
            acc[0][0] = __builtin_amdgcn_mfma_f32_16x16x32_fp8_fp8(a0.x, b0.x, acc[0][0], 0, 0, 0);
            acc[0][1] = __builtin_amdgcn_mfma_f32_16x16x32_fp8_fp8(a0.x, b1.x, acc[0][1], 0, 0, 0);
            acc[1][0] = __builtin_amdgcn_mfma_f32_16x16x32_fp8_fp8(a1.x, b0.x, acc[1][0], 0, 0, 0);
            acc[1][1] = __builtin_amdgcn_mfma_f32_16x16x32_fp8_fp8(a1.x, b1.x, acc[1][1], 0, 0, 0);
            acc[0][0] = __builtin_amdgcn_mfma_f32_16x16x32_fp8_fp8(a0.y, b0.y, acc[0][0], 0, 0, 0);
            acc[0][1] = __builtin_amdgcn_mfma_f32_16x16x32_fp8_fp8(a0.y, b1.y, acc[0][1], 0, 0, 0);
            acc[1][0] = __builtin_amdgcn_mfma_f32_16x16x32_fp8_fp8(a1.y, b0.y, acc[1][0], 0, 0, 0);
            acc[1][1] = __builtin_amdgcn_mfma_f32_16x16x32_fp8_fp8(a1.y, b1.y, acc[1][1], 0, 0, 0);
        }
    };

    STAGE(0, 0);
    STAGE(1, 1);
    for (int t = 0; t < NT; ++t) {
        if (t < NT - 1) { asm volatile("s_waitcnt vmcnt(3)" ::: "memory"); }
        else            { asm volatile("s_waitcnt vmcnt(0)" ::: "memory"); }
        __builtin_amdgcn_s_barrier();
        __builtin_amdgcn_sched_barrier(0);
        if (t + 2 < NT) STAGE((t + 2) % 3, t + 2);
        COMPUTE(t % 3);
    }

    // ---- vectorized epilogue ----
    __syncthreads();                       // staging LDS now free
    float* T   = (float*)Al;               // [128][66] floats = 33792B < 48KB
    float* bev = (float*)Bl;               // [64]
    float* ctv = bev + 64;                 // [64]

    // scatter acc -> T (rows stride 66: 4-row offsets 0,8,16,24 -> <=2-way)
    #pragma unroll
    for (int m = 0; m < 2; ++m)
        #pragma unroll
        for (int n = 0; n < 2; ++n) {
            const int lr = wm * 32 + m * 16 + q * 4;
            const int lc = wn * 32 + n * 16 + r;
            #pragma unroll
            for (int rr = 0; rr < 4; ++rr)
                T[(lr + rr) * 66 + lc] = acc[m][n][rr];
        }
    // 64 threads compute per-column be/ct once
    if (tid < 64) {
        const int gc = bcol + tid;
        float bsum = 0.f;
        #pragma unroll 8
        for (int tk = 0; tk < 32; ++tk) bsum += partials[tk * 1024 + gc];
        bev[tid] = 0.1f * bsum;
        ctv[tid] = bias_lin[gc] + bias2[gc] + (float)NHID * wsum[gc];
    }
    __syncthreads();

    // gather + fused y term, f32x4 loads/stores (256B per row per wave)
    const int c4 = tid & 15, r0 = tid >> 4;      // rows r0, r0+32, r0+64, r0+96
    const f32x4 ct4 = *(const f32x4*)&ctv[c4 * 4];
    const f32x4 be4 = *(const f32x4*)&bev[c4 * 4];
    #pragma unroll
    for (int i = 0; i < 4; ++i) {
        const int row = r0 + i * 32;
        f32x4 v = *(const f32x4*)&T[row * 66 + c4 * 4];
        const size_t idx = (size_t)(brow + row) * N + bcol + c4 * 4;
        const f32x4 yv = *(const f32x4*)&y[idx];
        f32x4 o;
        #pragma unroll
        for (int e = 0; e < 4; ++e) o[e] = v[e] + ct4[e] - be4[e] * yv[e];
        *(f32x4*)&out[idx] = o;
    }
}

extern "C" void kernel_launch(void* const* d_in, const int* in_sizes, int n_in,
                              void* d_out, int out_size, void* d_ws, size_t ws_size,
                              hipStream_t stream) {
    const float* x        = (const float*)d_in[0];
    const float* y        = (const float*)d_in[1];
    const float* beta     = (const float*)d_in[2];
    const float* bias_lin = (const float*)d_in[3];
    const float* W2       = (const float*)d_in[5];
    const float* bias2    = (const float*)d_in[7];
    float* out = (float*)d_out;

    float* partials = (float*)d_ws;                        // [32][1024]
    float* wsum     = partials + 32 * 1024;                // [1024]
    char*  xb       = (char*)(wsum + 1024);                // [M][K] fp8 permuted
    char*  bts      = xb + (size_t)M * K;                  // [N][K] fp8 permuted

    pre_kernel<<<1792, 256, 0, stream>>>(x, beta, W2, xb, bts, partials, wsum);
    gemm_kernel<<<512, 512, 0, stream>>>(xb, bts, y, partials, wsum,
                                         bias_lin, bias2, out);
}